// Round 8
// baseline (154.263 us; speedup 1.0000x reference)
//
#include <hip/hip_runtime.h>
#include <math.h>

#define BATCH 8192
#define SENTS 50
#define ED    256
#define NENT  20
#define BB    16
#define NB    4          // batches per block (software pipeline)

// log2(200)/256
#define RATE_K 0.0298588132413075f

struct LoadSet {
    float4 xv[13];
    float4 qv;
    float4 ev[5];
};

// issue all global loads for one batch (straight-line, static destinations)
__device__ __forceinline__ void issue_loads(
    LoadSet& S, const float* __restrict__ sents,
    const float* __restrict__ entities, int b, int r, int c, bool has13)
{
    const float4* s4 = (const float4*)(sents + (size_t)b * SENTS * ED);
    const float4* e4 = (const float4*)(entities + (size_t)b * NENT * ED);
    #pragma unroll
    for (int k = 0; k < 12; ++k) S.xv[k] = s4[(r + 4 * k) * 64 + c];
    S.qv = s4[49 * 64 + c];
    #pragma unroll
    for (int n = 0; n < 5; ++n) S.ev[n] = e4[(r + 4 * n) * 64 + c];
    if (has13) S.xv[12] = s4[(r + 48) * 64 + c];
}

// ---------------------------------------------------------------------------
// Kernel A: 256 threads = 4 waves. Wave r owns rows s = r+4k (12-13 rows),
// lane c owns float4 cols [4c..4c+3]. Per-wave LOCAL softmax partials
// (m_r, d_r, h_r) -> LDS -> ONE raw s_barrier (lgkmcnt only, NO vmcnt
// drain) -> log-sum-exp merge. Each block pipelines NB batches: batch j+1
// loads issued before batch j compute, staying in flight across the
// barrier. LDS double-buffered by batch parity (no 2nd barrier).
// ---------------------------------------------------------------------------
__global__ __launch_bounds__(256) void attn_ent_kernel(
    const float* __restrict__ sents, const float* __restrict__ entities,
    const float* __restrict__ dense_w,
    float* __restrict__ h_out, float* __restrict__ m_out)
{
    __shared__ __align__(16) float hp[2][4][ED];
    __shared__ __align__(16) float ep[2][4][ED];
    __shared__ float md[2][4][2];

    int t  = threadIdx.x;
    int c  = t & 63;
    int r  = t >> 6;          // wave id = row residue, 0..3
    int b0 = blockIdx.x * NB;
    bool has13 = (r < 2);     // k=12 row: 48 (r=0), 49 (r=1)

    // per-lane column rates + per-thread dense_w element (loop-invariant)
    float4 rate;
    rate.x = exp2f(-(float)(4 * c + 0) * RATE_K);
    rate.y = exp2f(-(float)(4 * c + 1) * RATE_K);
    rate.z = exp2f(-(float)(4 * c + 2) * RATE_K);
    rate.w = exp2f(-(float)(4 * c + 3) * RATE_K);
    float wt = dense_w[t];

    LoadSet sA, sB;
    issue_loads(sA, sents, entities, b0, r, c, has13);

    #pragma unroll
    for (int j = 0; j < NB; ++j) {
        // ---- prefetch next batch into the other set (stays in flight) ----
        if (j + 1 < NB) {
            if ((j & 1) == 0) issue_loads(sB, sents, entities, b0 + j + 1, r, c, has13);
            else              issue_loads(sA, sents, entities, b0 + j + 1, r, c, has13);
        }
        LoadSet& S = ((j & 1) == 0) ? sA : sB;
        const int P = j & 1;
        const int b = b0 + j;

        // ---- q = sents[49] + pos[49] ----
        float4 q;
        q.x = S.qv.x + __sinf(49.f * rate.x);
        q.y = S.qv.y + __sinf(49.f * rate.y);
        q.z = S.qv.z + __sinf(49.f * rate.z);
        q.w = S.qv.w + __sinf(49.f * rate.w);

        // ---- x = sents + pos; per-row logits via 64-lane butterfly ----
        float4 x[13];
        float  lg[13];
        #pragma unroll
        for (int k = 0; k < 13; ++k) {
            if (k < 12 || has13) {
                float fs = (float)(r + 4 * k);
                x[k].x = S.xv[k].x + __sinf(fs * rate.x);
                x[k].y = S.xv[k].y + __sinf(fs * rate.y);
                x[k].z = S.xv[k].z + __sinf(fs * rate.z);
                x[k].w = S.xv[k].w + __sinf(fs * rate.w);
                float p = x[k].x * q.x + x[k].y * q.y + x[k].z * q.z + x[k].w * q.w;
                p += __shfl_xor(p, 1);
                p += __shfl_xor(p, 2);
                p += __shfl_xor(p, 4);
                p += __shfl_xor(p, 8);
                p += __shfl_xor(p, 16);
                p += __shfl_xor(p, 32);
                lg[k] = p;
            }
        }

        // ---- wave-local softmax partial over own rows ----
        float mr = lg[0];
        #pragma unroll
        for (int k = 1; k < 13; ++k)
            if (k < 12 || has13) mr = fmaxf(mr, lg[k]);

        float dr = 0.f;
        float4 hacc = make_float4(0.f, 0.f, 0.f, 0.f);
        #pragma unroll
        for (int k = 0; k < 13; ++k) {
            if (k < 12 || has13) {
                float w = __expf(lg[k] - mr);
                dr += w;
                hacc.x += w * x[k].x; hacc.y += w * x[k].y;
                hacc.z += w * x[k].z; hacc.w += w * x[k].w;
            }
        }

        // ---- entity partial ----
        float4 es;
        es.x = ((S.ev[0].x + S.ev[1].x) + (S.ev[2].x + S.ev[3].x)) + S.ev[4].x;
        es.y = ((S.ev[0].y + S.ev[1].y) + (S.ev[2].y + S.ev[3].y)) + S.ev[4].y;
        es.z = ((S.ev[0].z + S.ev[1].z) + (S.ev[2].z + S.ev[3].z)) + S.ev[4].z;
        es.w = ((S.ev[0].w + S.ev[1].w) + (S.ev[2].w + S.ev[3].w)) + S.ev[4].w;

        // ---- publish partials to LDS ----
        *(float4*)&hp[P][r][4 * c] = hacc;
        *(float4*)&ep[P][r][4 * c] = es;
        if (c == 0) { md[P][r][0] = mr; md[P][r][1] = dr; }

        // ---- raw barrier: wait LDS only, vmcnt (prefetch) stays in flight ----
        asm volatile("s_waitcnt lgkmcnt(0)" ::: "memory");
        __builtin_amdgcn_s_barrier();
        asm volatile("" ::: "memory");

        // ---- log-sum-exp merge across 4 waves; thread t owns column t ----
        float m0 = md[P][0][0], d0 = md[P][0][1];
        float m1 = md[P][1][0], d1 = md[P][1][1];
        float m2 = md[P][2][0], d2 = md[P][2][1];
        float m3 = md[P][3][0], d3 = md[P][3][1];
        float M  = fmaxf(fmaxf(m0, m1), fmaxf(m2, m3));
        float s0 = __expf(m0 - M), s1 = __expf(m1 - M);
        float s2 = __expf(m2 - M), s3 = __expf(m3 - M);
        float dd = s0 * d0 + s1 * d1 + s2 * d2 + s3 * d3;
        float hv = s0 * hp[P][0][t] + s1 * hp[P][1][t]
                 + s2 * hp[P][2][t] + s3 * hp[P][3][t];
        h_out[(size_t)b * ED + t] = hv / dd;

        float ev = (ep[P][0][t] + ep[P][1][t]) + (ep[P][2][t] + ep[P][3][t]);
        m_out[(size_t)b * ED + t] = ev * wt;
        // no 2nd barrier: next batch uses opposite LDS parity; reuse of this
        // parity is fenced by the NEXT batch's barrier (program order).
    }
}

// ---------------------------------------------------------------------------
// Kernel 2: out[b] = sigmoid( sum_e (sum_e' h[e'] A[e',e]) * m[e] + bias )
// BB batches per block; coalesced column reads of A (L2-resident).
// ---------------------------------------------------------------------------
__global__ __launch_bounds__(256) void bilinear_kernel(
    const float* __restrict__ hws, const float* __restrict__ mws,
    const float* __restrict__ A, const float* __restrict__ dense_b,
    float* __restrict__ out)
{
    __shared__ __align__(16) float hl[BB][ED];
    __shared__ float ml[BB][ED];
    __shared__ float part[BB][ED];

    int t  = threadIdx.x;
    int b0 = blockIdx.x * BB;

    for (int i = 0; i < BB; ++i) {
        hl[i][t] = hws[(size_t)(b0 + i) * ED + t];
        ml[i][t] = mws[(size_t)(b0 + i) * ED + t];
    }
    __syncthreads();

    float acc[BB];
    #pragma unroll
    for (int i = 0; i < BB; ++i) acc[i] = 0.f;

    for (int ep = 0; ep < ED; ep += 4) {
        float a0 = A[(ep + 0) * ED + t];
        float a1 = A[(ep + 1) * ED + t];
        float a2 = A[(ep + 2) * ED + t];
        float a3 = A[(ep + 3) * ED + t];
        #pragma unroll
        for (int i = 0; i < BB; ++i) {
            float4 hv = *(const float4*)&hl[i][ep];
            acc[i] += hv.x * a0 + hv.y * a1 + hv.z * a2 + hv.w * a3;
        }
    }

    #pragma unroll
    for (int i = 0; i < BB; ++i) part[i][t] = acc[i] * ml[i][t];
    __syncthreads();

    int lane = t & 63, w = t >> 6;
    float bias = dense_b[0];
    for (int i = w; i < BB; i += 4) {
        float v = part[i][lane] + part[i][lane + 64] + part[i][lane + 128] + part[i][lane + 192];
        for (int off = 32; off >= 1; off >>= 1) v += __shfl_xor(v, off);
        if (lane == 0) out[b0 + i] = 1.f / (1.f + expf(-(v + bias)));
    }
}

// ---------------------------------------------------------------------------
// Fallback: fully fused, no workspace (in case ws_size is tiny)
// ---------------------------------------------------------------------------
__global__ __launch_bounds__(256) void fused_kernel(
    const float* __restrict__ sents, const float* __restrict__ entities,
    const float* __restrict__ A, const float* __restrict__ dense_w,
    const float* __restrict__ dense_b, float* __restrict__ out)
{
    __shared__ __align__(16) float xs[SENTS][ED + 4];
    __shared__ float logit_s[64];
    __shared__ float coef[64];
    __shared__ __align__(16) float harr[ED];
    __shared__ float marr[ED];
    __shared__ float red[4];

    int t    = threadIdx.x;
    int b    = blockIdx.x;
    int lane = t & 63;
    int w    = t >> 6;

    float rate = exp2f(-(float)t * RATE_K);
    const float* sp = sents + (size_t)b * SENTS * ED;
    for (int s = 0; s < SENTS; ++s)
        xs[s][t] = sp[s * ED + t] + sinf((float)s * rate);
    __syncthreads();

    float4 q = *(const float4*)&xs[SENTS - 1][lane * 4];
    for (int s = w; s < SENTS; s += 4) {
        float4 v = *(const float4*)&xs[s][lane * 4];
        float p = v.x * q.x + v.y * q.y + v.z * q.z + v.w * q.w;
        p += __shfl_down(p, 32);
        p += __shfl_down(p, 16);
        p += __shfl_down(p, 8);
        p += __shfl_down(p, 4);
        p += __shfl_down(p, 2);
        p += __shfl_down(p, 1);
        if (lane == 0) logit_s[s] = p;
    }
    __syncthreads();

    if (w == 0) {
        float l = (lane < SENTS) ? logit_s[lane] : -INFINITY;
        float mx = l;
        for (int off = 32; off >= 1; off >>= 1) mx = fmaxf(mx, __shfl_xor(mx, off));
        float ex = (lane < SENTS) ? expf(l - mx) : 0.f;
        float sm = ex;
        for (int off = 32; off >= 1; off >>= 1) sm += __shfl_xor(sm, off);
        if (lane < SENTS) coef[lane] = ex / sm;
    }
    __syncthreads();

    float h = 0.f;
    #pragma unroll
    for (int s = 0; s < SENTS; ++s) h += coef[s] * xs[s][t];

    const float* ent = entities + (size_t)b * NENT * ED;
    float es = 0.f;
    #pragma unroll
    for (int n = 0; n < NENT; ++n) es += ent[n * ED + t];
    float m = es * dense_w[t];

    harr[t] = h;
    marr[t] = m;
    __syncthreads();

    float acc = 0.f;
    for (int ep = 0; ep < ED; ep += 4) {
        float4 hv = *(const float4*)&harr[ep];
        acc += hv.x * A[(ep + 0) * ED + t];
        acc += hv.y * A[(ep + 1) * ED + t];
        acc += hv.z * A[(ep + 2) * ED + t];
        acc += hv.w * A[(ep + 3) * ED + t];
    }
    float val = acc * marr[t];
    val += __shfl_down(val, 32);
    val += __shfl_down(val, 16);
    val += __shfl_down(val, 8);
    val += __shfl_down(val, 4);
    val += __shfl_down(val, 2);
    val += __shfl_down(val, 1);
    if (lane == 0) red[w] = val;
    __syncthreads();
    if (t == 0) {
        float tot = red[0] + red[1] + red[2] + red[3];
        out[b] = 1.f / (1.f + expf(-(tot + dense_b[0])));
    }
}

extern "C" void kernel_launch(void* const* d_in, const int* in_sizes, int n_in,
                              void* d_out, int out_size, void* d_ws, size_t ws_size,
                              hipStream_t stream) {
    const float* sents    = (const float*)d_in[0];
    const float* entities = (const float*)d_in[1];
    const float* A        = (const float*)d_in[2];
    const float* dense_w  = (const float*)d_in[3];
    const float* dense_b  = (const float*)d_in[4];
    float* out = (float*)d_out;

    size_t hm_bytes = (size_t)BATCH * ED * sizeof(float);           // 8 MB each
    size_t need = 2 * hm_bytes;

    if (ws_size >= need) {
        float* hws = (float*)d_ws;
        float* mws = (float*)((char*)d_ws + hm_bytes);
        attn_ent_kernel<<<BATCH / NB, 256, 0, stream>>>(sents, entities, dense_w, hws, mws);
        bilinear_kernel<<<BATCH / BB, 256, 0, stream>>>(hws, mws, A, dense_b, out);
    } else {
        fused_kernel<<<BATCH, 256, 0, stream>>>(sents, entities, A, dense_w, dense_b, out);
    }
}

// Round 9
// 143.763 us; speedup vs baseline: 1.0730x; 1.0730x over previous
//
#include <hip/hip_runtime.h>
#include <math.h>

#define BATCH 8192
#define SENTS 50
#define ED    256
#define NENT  20
#define BB    16

// log2(200)/256
#define RATE_K 0.0298588132413075f

// ---------------------------------------------------------------------------
// Kernel 0: AT = A^T (so the matvec reads coalesced). 256 blocks x 256 thr,
// 16x16 LDS tiles (+1 pad). ~256 KB, ~2 us.
// ---------------------------------------------------------------------------
__global__ __launch_bounds__(256) void at_kernel(
    const float* __restrict__ A, float* __restrict__ AT)
{
    __shared__ float tile[16][17];
    int t  = threadIdx.x;
    int tx = t & 15, ty = t >> 4;
    int bi = blockIdx.x & 15, bj = blockIdx.x >> 4;

    tile[ty][tx] = A[(bi * 16 + ty) * ED + (bj * 16 + tx)];
    __syncthreads();
    AT[(bj * 16 + ty) * ED + (bi * 16 + tx)] = tile[tx][ty];
}

// ---------------------------------------------------------------------------
// Kernel 1: m[b,e] = (sum_n entities[b,n,e]) * w[e]. Pure streaming reduce,
// no LDS, no barriers; 20 float4 loads issued up front per thread.
// ---------------------------------------------------------------------------
__global__ __launch_bounds__(256) void ent_kernel(
    const float* __restrict__ entities, const float* __restrict__ dense_w,
    float* __restrict__ m_out)
{
    int t = threadIdx.x;
    int b = blockIdx.x * 4 + (t >> 6);
    int c = t & 63;

    const float4* e4 = (const float4*)(entities + (size_t)b * NENT * ED);

    float4 a[NENT];
    #pragma unroll
    for (int n = 0; n < NENT; ++n) a[n] = e4[n * 64 + c];

    float4 s = make_float4(0.f, 0.f, 0.f, 0.f);
    #pragma unroll
    for (int n = 0; n < NENT; ++n) {
        s.x += a[n].x; s.y += a[n].y; s.z += a[n].z; s.w += a[n].w;
    }

    float4 w4 = ((const float4*)dense_w)[c];
    s.x *= w4.x; s.y *= w4.y; s.z *= w4.z; s.w *= w4.w;
    ((float4*)(m_out + (size_t)b * ED))[c] = s;
}

// ---------------------------------------------------------------------------
// Kernel 2: v[b,e'] = sum_e A[e',e] m[b,e] = sum_e AT[e,e'] m[b,e].
// BB batches per block; coalesced AT column reads (L2-resident).
// ---------------------------------------------------------------------------
__global__ __launch_bounds__(256) void matvec_kernel(
    const float* __restrict__ mws, const float* __restrict__ AT,
    float* __restrict__ vws)
{
    __shared__ __align__(16) float ml[BB][ED];

    int t  = threadIdx.x;
    int b0 = blockIdx.x * BB;

    for (int i = 0; i < BB; ++i)
        ml[i][t] = mws[(size_t)(b0 + i) * ED + t];
    __syncthreads();

    float acc[BB];
    #pragma unroll
    for (int i = 0; i < BB; ++i) acc[i] = 0.f;

    for (int e = 0; e < ED; e += 4) {
        float a0 = AT[(e + 0) * ED + t];
        float a1 = AT[(e + 1) * ED + t];
        float a2 = AT[(e + 2) * ED + t];
        float a3 = AT[(e + 3) * ED + t];
        #pragma unroll
        for (int i = 0; i < BB; ++i) {
            float4 mv = *(const float4*)&ml[i][e];
            acc[i] += mv.x * a0 + mv.y * a1 + mv.z * a2 + mv.w * a3;
        }
    }

    #pragma unroll
    for (int i = 0; i < BB; ++i)
        vws[(size_t)(b0 + i) * ED + t] = acc[i];
}

// ---------------------------------------------------------------------------
// Kernel 3: out[b] = sigmoid( sum_s coef[s] * (x[s].v[b]) + bias ),
// coef = softmax_s(x[s].x[49]). One block per batch, 256 thr = 4 waves;
// wave r owns rows s = r+4k, lane c owns float4 cols. x consumed at arrival
// (never stored): per row -> logit partial (butterfly) + z-partial (lane-
// local). Tail: softmax in-lane + tiny reduce; ONE scalar store per batch.
// ---------------------------------------------------------------------------
__global__ __launch_bounds__(256) void sents_kernel(
    const float* __restrict__ sents, const float* __restrict__ vws,
    const float* __restrict__ dense_b, float* __restrict__ out)
{
    __shared__ float lgs[64];
    __shared__ float wred[4];

    int t = threadIdx.x;
    int c = t & 63;
    int r = t >> 6;           // wave id = row residue 0..3
    int b = blockIdx.x;
    bool has13 = (r < 2);     // k=12 row: 48 (r=0), 49 (r=1)

    const float4* s4 = (const float4*)(sents + (size_t)b * SENTS * ED);

    // ---- issue ALL loads up front (q/v first: needed earliest) ----
    float4 qv = s4[49 * 64 + c];
    float4 vv = ((const float4*)(vws + (size_t)b * ED))[c];
    float4 xv[13];
    #pragma unroll
    for (int k = 0; k < 12; ++k) xv[k] = s4[(r + 4 * k) * 64 + c];
    if (has13) xv[12] = s4[(r + 48) * 64 + c];

    // ---- per-lane column rates (VALU under load latency) ----
    float4 rate;
    rate.x = exp2f(-(float)(4 * c + 0) * RATE_K);
    rate.y = exp2f(-(float)(4 * c + 1) * RATE_K);
    rate.z = exp2f(-(float)(4 * c + 2) * RATE_K);
    rate.w = exp2f(-(float)(4 * c + 3) * RATE_K);

    float4 q;
    q.x = qv.x + __sinf(49.f * rate.x);
    q.y = qv.y + __sinf(49.f * rate.y);
    q.z = qv.z + __sinf(49.f * rate.z);
    q.w = qv.w + __sinf(49.f * rate.w);

    // ---- stream rows: logit butterfly + lane-local z-partial; x dies ----
    float zp[13];
    #pragma unroll
    for (int k = 0; k < 13; ++k) {
        if (k < 12 || has13) {
            float fs = (float)(r + 4 * k);
            float4 x;
            x.x = xv[k].x + __sinf(fs * rate.x);
            x.y = xv[k].y + __sinf(fs * rate.y);
            x.z = xv[k].z + __sinf(fs * rate.z);
            x.w = xv[k].w + __sinf(fs * rate.w);

            zp[k] = x.x * vv.x + x.y * vv.y + x.z * vv.z + x.w * vv.w;

            float p = x.x * q.x + x.y * q.y + x.z * q.z + x.w * q.w;
            p += __shfl_xor(p, 1);
            p += __shfl_xor(p, 2);
            p += __shfl_xor(p, 4);
            p += __shfl_xor(p, 8);
            p += __shfl_xor(p, 16);
            p += __shfl_xor(p, 32);
            if (c == 0) lgs[r + 4 * k] = p;
        } else {
            zp[k] = 0.f;
        }
    }
    __syncthreads();

    // ---- softmax over 50 logits (all waves redundantly, in-lane) ----
    float lg = (c < SENTS) ? lgs[c] : -INFINITY;
    float mx = lg;
    mx = fmaxf(mx, __shfl_xor(mx, 1));
    mx = fmaxf(mx, __shfl_xor(mx, 2));
    mx = fmaxf(mx, __shfl_xor(mx, 4));
    mx = fmaxf(mx, __shfl_xor(mx, 8));
    mx = fmaxf(mx, __shfl_xor(mx, 16));
    mx = fmaxf(mx, __shfl_xor(mx, 32));
    float ex = (c < SENTS) ? __expf(lg - mx) : 0.f;
    float sm = ex;
    sm += __shfl_xor(sm, 1);
    sm += __shfl_xor(sm, 2);
    sm += __shfl_xor(sm, 4);
    sm += __shfl_xor(sm, 8);
    sm += __shfl_xor(sm, 16);
    sm += __shfl_xor(sm, 32);
    float coef = ex / sm;     // lane c holds coef[c] for c < 50

    // ---- acc = sum_k coef[r+4k] * zp[k]; butterfly; cross-wave reduce ----
    float acc = 0.f;
    #pragma unroll
    for (int k = 0; k < 13; ++k) {
        if (k < 12 || has13)
            acc += __shfl(coef, r + 4 * k) * zp[k];
    }
    acc += __shfl_xor(acc, 1);
    acc += __shfl_xor(acc, 2);
    acc += __shfl_xor(acc, 4);
    acc += __shfl_xor(acc, 8);
    acc += __shfl_xor(acc, 16);
    acc += __shfl_xor(acc, 32);
    if (c == 0) wred[r] = acc;
    __syncthreads();

    if (t == 0) {
        float tot = (wred[0] + wred[1]) + (wred[2] + wred[3]);
        out[b] = 1.f / (1.f + __expf(-(tot + dense_b[0])));
    }
}

// ---------------------------------------------------------------------------
// Fallback: fully fused, no workspace (in case ws_size is tiny)
// ---------------------------------------------------------------------------
__global__ __launch_bounds__(256) void fused_kernel(
    const float* __restrict__ sents, const float* __restrict__ entities,
    const float* __restrict__ A, const float* __restrict__ dense_w,
    const float* __restrict__ dense_b, float* __restrict__ out)
{
    __shared__ __align__(16) float xs[SENTS][ED + 4];
    __shared__ float logit_s[64];
    __shared__ float coef[64];
    __shared__ __align__(16) float harr[ED];
    __shared__ float marr[ED];
    __shared__ float red[4];

    int t    = threadIdx.x;
    int b    = blockIdx.x;
    int lane = t & 63;
    int w    = t >> 6;

    float rate = exp2f(-(float)t * RATE_K);
    const float* sp = sents + (size_t)b * SENTS * ED;
    for (int s = 0; s < SENTS; ++s)
        xs[s][t] = sp[s * ED + t] + sinf((float)s * rate);
    __syncthreads();

    float4 q = *(const float4*)&xs[SENTS - 1][lane * 4];
    for (int s = w; s < SENTS; s += 4) {
        float4 v = *(const float4*)&xs[s][lane * 4];
        float p = v.x * q.x + v.y * q.y + v.z * q.z + v.w * q.w;
        p += __shfl_down(p, 32);
        p += __shfl_down(p, 16);
        p += __shfl_down(p, 8);
        p += __shfl_down(p, 4);
        p += __shfl_down(p, 2);
        p += __shfl_down(p, 1);
        if (lane == 0) logit_s[s] = p;
    }
    __syncthreads();

    if (w == 0) {
        float l = (lane < SENTS) ? logit_s[lane] : -INFINITY;
        float mx = l;
        for (int off = 32; off >= 1; off >>= 1) mx = fmaxf(mx, __shfl_xor(mx, off));
        float ex = (lane < SENTS) ? expf(l - mx) : 0.f;
        float sm = ex;
        for (int off = 32; off >= 1; off >>= 1) sm += __shfl_xor(sm, off);
        if (lane < SENTS) coef[lane] = ex / sm;
    }
    __syncthreads();

    float h = 0.f;
    #pragma unroll
    for (int s = 0; s < SENTS; ++s) h += coef[s] * xs[s][t];

    const float* ent = entities + (size_t)b * NENT * ED;
    float es = 0.f;
    #pragma unroll
    for (int n = 0; n < NENT; ++n) es += ent[n * ED + t];
    float m = es * dense_w[t];

    harr[t] = h;
    marr[t] = m;
    __syncthreads();

    float acc = 0.f;
    for (int ep = 0; ep < ED; ep += 4) {
        float4 hv = *(const float4*)&harr[ep];
        acc += hv.x * A[(ep + 0) * ED + t];
        acc += hv.y * A[(ep + 1) * ED + t];
        acc += hv.z * A[(ep + 2) * ED + t];
        acc += hv.w * A[(ep + 3) * ED + t];
    }
    float val = acc * marr[t];
    val += __shfl_down(val, 32);
    val += __shfl_down(val, 16);
    val += __shfl_down(val, 8);
    val += __shfl_down(val, 4);
    val += __shfl_down(val, 2);
    val += __shfl_down(val, 1);
    if (lane == 0) red[w] = val;
    __syncthreads();
    if (t == 0) {
        float tot = red[0] + red[1] + red[2] + red[3];
        out[b] = 1.f / (1.f + expf(-(tot + dense_b[0])));
    }
}

extern "C" void kernel_launch(void* const* d_in, const int* in_sizes, int n_in,
                              void* d_out, int out_size, void* d_ws, size_t ws_size,
                              hipStream_t stream) {
    const float* sents    = (const float*)d_in[0];
    const float* entities = (const float*)d_in[1];
    const float* A        = (const float*)d_in[2];
    const float* dense_w  = (const float*)d_in[3];
    const float* dense_b  = (const float*)d_in[4];
    float* out = (float*)d_out;

    size_t hm_bytes = (size_t)BATCH * ED * sizeof(float);           // 8 MB each
    size_t at_bytes = (size_t)ED * ED * sizeof(float);              // 256 KB
    size_t need = 2 * hm_bytes + at_bytes;

    if (ws_size >= need) {
        float* mws = (float*)d_ws;
        float* vws = (float*)((char*)d_ws + hm_bytes);
        float* ATw = (float*)((char*)d_ws + 2 * hm_bytes);
        at_kernel<<<256, 256, 0, stream>>>(A, ATw);
        ent_kernel<<<BATCH / 4, 256, 0, stream>>>(entities, dense_w, mws);
        matvec_kernel<<<BATCH / BB, 256, 0, stream>>>(mws, ATw, vws);
        sents_kernel<<<BATCH, 256, 0, stream>>>(sents, vws, dense_b, out);
    } else {
        fused_kernel<<<BATCH, 256, 0, stream>>>(sents, entities, A, dense_w, dense_b, out);
    }
}

// Round 10
// 137.466 us; speedup vs baseline: 1.1222x; 1.0458x over previous
//
#include <hip/hip_runtime.h>
#include <math.h>

#define BATCH 8192
#define SENTS 50
#define ED    256
#define NENT  20
#define BB    16

#define ENT_BLOCKS (BATCH / 4)     // 2048
#define AT_BLOCKS  256

// log2(200)/256
#define RATE_K 0.0298588132413075f

typedef float f4 __attribute__((ext_vector_type(4)));

// ---------------------------------------------------------------------------
// Kernel 0 (fat): blocks [0, ENT_BLOCKS) -> entity reduce (nt loads);
//                 blocks [ENT_BLOCKS, +AT_BLOCKS) -> A transpose.
// ent: m[b,e] = (sum_n entities[b,n,e]) * w[e]; pure stream, no barriers.
// at : AT = A^T via 16x16 LDS tiles.
// ---------------------------------------------------------------------------
__global__ __launch_bounds__(256) void ent_at_kernel(
    const float* __restrict__ entities, const float* __restrict__ dense_w,
    const float* __restrict__ A,
    float* __restrict__ m_out, float* __restrict__ AT)
{
    __shared__ float tile[16][17];
    int t = threadIdx.x;

    if (blockIdx.x < ENT_BLOCKS) {
        int b = blockIdx.x * 4 + (t >> 6);
        int c = t & 63;

        const f4* e4 = (const f4*)(entities + (size_t)b * NENT * ED);

        f4 a[NENT];
        #pragma unroll
        for (int n = 0; n < NENT; ++n)
            a[n] = __builtin_nontemporal_load(&e4[n * 64 + c]);

        f4 s = (f4)0.f;
        #pragma unroll
        for (int n = 0; n < NENT; ++n) s += a[n];

        f4 w4 = ((const f4*)dense_w)[c];
        s *= w4;
        ((f4*)(m_out + (size_t)b * ED))[c] = s;
    } else {
        int bid = blockIdx.x - ENT_BLOCKS;
        int tx = t & 15, ty = t >> 4;
        int bi = bid & 15, bj = bid >> 4;

        tile[ty][tx] = A[(bi * 16 + ty) * ED + (bj * 16 + tx)];
        __syncthreads();
        AT[(bj * 16 + ty) * ED + (bi * 16 + tx)] = tile[tx][ty];
    }
}

// ---------------------------------------------------------------------------
// Kernel 1: v[b,e'] = sum_e AT[e,e'] m[b,e]. BB batches per block;
// coalesced AT column reads (L2-resident); LDS broadcast reads of m.
// ---------------------------------------------------------------------------
__global__ __launch_bounds__(256) void matvec_kernel(
    const float* __restrict__ mws, const float* __restrict__ AT,
    float* __restrict__ vws)
{
    __shared__ __align__(16) float ml[BB][ED];

    int t  = threadIdx.x;
    int b0 = blockIdx.x * BB;

    for (int i = 0; i < BB; ++i)
        ml[i][t] = mws[(size_t)(b0 + i) * ED + t];
    __syncthreads();

    float acc[BB];
    #pragma unroll
    for (int i = 0; i < BB; ++i) acc[i] = 0.f;

    for (int e = 0; e < ED; e += 4) {
        float a0 = AT[(e + 0) * ED + t];
        float a1 = AT[(e + 1) * ED + t];
        float a2 = AT[(e + 2) * ED + t];
        float a3 = AT[(e + 3) * ED + t];
        #pragma unroll
        for (int i = 0; i < BB; ++i) {
            float4 mv = *(const float4*)&ml[i][e];
            acc[i] += mv.x * a0 + mv.y * a1 + mv.z * a2 + mv.w * a3;
        }
    }

    #pragma unroll
    for (int i = 0; i < BB; ++i)
        vws[(size_t)(b0 + i) * ED + t] = acc[i];
}

// ---------------------------------------------------------------------------
// Kernel 2: out[b] = sigmoid( sum_s coef[s] * (x[s].v[b]) + bias ),
// coef = softmax_s(x[s].x[49]). One block per batch, 4 waves; wave r owns
// rows s = r+4k, lane c owns float4 cols. x consumed at arrival.
// ---------------------------------------------------------------------------
__global__ __launch_bounds__(256) void sents_kernel(
    const float* __restrict__ sents, const float* __restrict__ vws,
    const float* __restrict__ dense_b, float* __restrict__ out)
{
    __shared__ float lgs[64];
    __shared__ float wred[4];

    int t = threadIdx.x;
    int c = t & 63;
    int r = t >> 6;
    int b = blockIdx.x;
    bool has13 = (r < 2);

    const float4* s4 = (const float4*)(sents + (size_t)b * SENTS * ED);

    float4 qv = s4[49 * 64 + c];
    float4 vv = ((const float4*)(vws + (size_t)b * ED))[c];
    float4 xv[13];
    #pragma unroll
    for (int k = 0; k < 12; ++k) xv[k] = s4[(r + 4 * k) * 64 + c];
    if (has13) xv[12] = s4[(r + 48) * 64 + c];

    float4 rate;
    rate.x = exp2f(-(float)(4 * c + 0) * RATE_K);
    rate.y = exp2f(-(float)(4 * c + 1) * RATE_K);
    rate.z = exp2f(-(float)(4 * c + 2) * RATE_K);
    rate.w = exp2f(-(float)(4 * c + 3) * RATE_K);

    float4 q;
    q.x = qv.x + __sinf(49.f * rate.x);
    q.y = qv.y + __sinf(49.f * rate.y);
    q.z = qv.z + __sinf(49.f * rate.z);
    q.w = qv.w + __sinf(49.f * rate.w);

    float zp[13];
    #pragma unroll
    for (int k = 0; k < 13; ++k) {
        if (k < 12 || has13) {
            float fs = (float)(r + 4 * k);
            float4 x;
            x.x = xv[k].x + __sinf(fs * rate.x);
            x.y = xv[k].y + __sinf(fs * rate.y);
            x.z = xv[k].z + __sinf(fs * rate.z);
            x.w = xv[k].w + __sinf(fs * rate.w);

            zp[k] = x.x * vv.x + x.y * vv.y + x.z * vv.z + x.w * vv.w;

            float p = x.x * q.x + x.y * q.y + x.z * q.z + x.w * q.w;
            p += __shfl_xor(p, 1);
            p += __shfl_xor(p, 2);
            p += __shfl_xor(p, 4);
            p += __shfl_xor(p, 8);
            p += __shfl_xor(p, 16);
            p += __shfl_xor(p, 32);
            if (c == 0) lgs[r + 4 * k] = p;
        } else {
            zp[k] = 0.f;
        }
    }
    __syncthreads();

    float lg = (c < SENTS) ? lgs[c] : -INFINITY;
    float mx = lg;
    mx = fmaxf(mx, __shfl_xor(mx, 1));
    mx = fmaxf(mx, __shfl_xor(mx, 2));
    mx = fmaxf(mx, __shfl_xor(mx, 4));
    mx = fmaxf(mx, __shfl_xor(mx, 8));
    mx = fmaxf(mx, __shfl_xor(mx, 16));
    mx = fmaxf(mx, __shfl_xor(mx, 32));
    float ex = (c < SENTS) ? __expf(lg - mx) : 0.f;
    float sm = ex;
    sm += __shfl_xor(sm, 1);
    sm += __shfl_xor(sm, 2);
    sm += __shfl_xor(sm, 4);
    sm += __shfl_xor(sm, 8);
    sm += __shfl_xor(sm, 16);
    sm += __shfl_xor(sm, 32);
    float coef = ex / sm;

    float acc = 0.f;
    #pragma unroll
    for (int k = 0; k < 13; ++k) {
        if (k < 12 || has13)
            acc += __shfl(coef, r + 4 * k) * zp[k];
    }
    acc += __shfl_xor(acc, 1);
    acc += __shfl_xor(acc, 2);
    acc += __shfl_xor(acc, 4);
    acc += __shfl_xor(acc, 8);
    acc += __shfl_xor(acc, 16);
    acc += __shfl_xor(acc, 32);
    if (c == 0) wred[r] = acc;
    __syncthreads();

    if (t == 0) {
        float tot = (wred[0] + wred[1]) + (wred[2] + wred[3]);
        out[b] = 1.f / (1.f + __expf(-(tot + dense_b[0])));
    }
}

// ---------------------------------------------------------------------------
// Fallback: fully fused, no workspace (in case ws_size is tiny)
// ---------------------------------------------------------------------------
__global__ __launch_bounds__(256) void fused_kernel(
    const float* __restrict__ sents, const float* __restrict__ entities,
    const float* __restrict__ A, const float* __restrict__ dense_w,
    const float* __restrict__ dense_b, float* __restrict__ out)
{
    __shared__ __align__(16) float xs[SENTS][ED + 4];
    __shared__ float logit_s[64];
    __shared__ float coef[64];
    __shared__ __align__(16) float harr[ED];
    __shared__ float marr[ED];
    __shared__ float red[4];

    int t    = threadIdx.x;
    int b    = blockIdx.x;
    int lane = t & 63;
    int w    = t >> 6;

    float rate = exp2f(-(float)t * RATE_K);
    const float* sp = sents + (size_t)b * SENTS * ED;
    for (int s = 0; s < SENTS; ++s)
        xs[s][t] = sp[s * ED + t] + sinf((float)s * rate);
    __syncthreads();

    float4 q = *(const float4*)&xs[SENTS - 1][lane * 4];
    for (int s = w; s < SENTS; s += 4) {
        float4 v = *(const float4*)&xs[s][lane * 4];
        float p = v.x * q.x + v.y * q.y + v.z * q.z + v.w * q.w;
        p += __shfl_down(p, 32);
        p += __shfl_down(p, 16);
        p += __shfl_down(p, 8);
        p += __shfl_down(p, 4);
        p += __shfl_down(p, 2);
        p += __shfl_down(p, 1);
        if (lane == 0) logit_s[s] = p;
    }
    __syncthreads();

    if (w == 0) {
        float l = (lane < SENTS) ? logit_s[lane] : -INFINITY;
        float mx = l;
        for (int off = 32; off >= 1; off >>= 1) mx = fmaxf(mx, __shfl_xor(mx, off));
        float ex = (lane < SENTS) ? expf(l - mx) : 0.f;
        float sm = ex;
        for (int off = 32; off >= 1; off >>= 1) sm += __shfl_xor(sm, off);
        if (lane < SENTS) coef[lane] = ex / sm;
    }
    __syncthreads();

    float h = 0.f;
    #pragma unroll
    for (int s = 0; s < SENTS; ++s) h += coef[s] * xs[s][t];

    const float* ent = entities + (size_t)b * NENT * ED;
    float es = 0.f;
    #pragma unroll
    for (int n = 0; n < NENT; ++n) es += ent[n * ED + t];
    float m = es * dense_w[t];

    harr[t] = h;
    marr[t] = m;
    __syncthreads();

    float acc = 0.f;
    for (int ep = 0; ep < ED; ep += 4) {
        float4 hv = *(const float4*)&harr[ep];
        acc += hv.x * A[(ep + 0) * ED + t];
        acc += hv.y * A[(ep + 1) * ED + t];
        acc += hv.z * A[(ep + 2) * ED + t];
        acc += hv.w * A[(ep + 3) * ED + t];
    }
    float val = acc * marr[t];
    val += __shfl_down(val, 32);
    val += __shfl_down(val, 16);
    val += __shfl_down(val, 8);
    val += __shfl_down(val, 4);
    val += __shfl_down(val, 2);
    val += __shfl_down(val, 1);
    if (lane == 0) red[w] = val;
    __syncthreads();
    if (t == 0) {
        float tot = red[0] + red[1] + red[2] + red[3];
        out[b] = 1.f / (1.f + expf(-(tot + dense_b[0])));
    }
}

extern "C" void kernel_launch(void* const* d_in, const int* in_sizes, int n_in,
                              void* d_out, int out_size, void* d_ws, size_t ws_size,
                              hipStream_t stream) {
    const float* sents    = (const float*)d_in[0];
    const float* entities = (const float*)d_in[1];
    const float* A        = (const float*)d_in[2];
    const float* dense_w  = (const float*)d_in[3];
    const float* dense_b  = (const float*)d_in[4];
    float* out = (float*)d_out;

    size_t hm_bytes = (size_t)BATCH * ED * sizeof(float);           // 8 MB each
    size_t at_bytes = (size_t)ED * ED * sizeof(float);              // 256 KB
    size_t need = 2 * hm_bytes + at_bytes;

    if (ws_size >= need) {
        float* mws = (float*)d_ws;
        float* vws = (float*)((char*)d_ws + hm_bytes);
        float* ATw = (float*)((char*)d_ws + 2 * hm_bytes);
        ent_at_kernel<<<ENT_BLOCKS + AT_BLOCKS, 256, 0, stream>>>(
            entities, dense_w, A, mws, ATw);
        matvec_kernel<<<BATCH / BB, 256, 0, stream>>>(mws, ATw, vws);
        sents_kernel<<<BATCH, 256, 0, stream>>>(sents, vws, dense_b, out);
    } else {
        fused_kernel<<<BATCH, 256, 0, stream>>>(sents, entities, A, dense_w, dense_b, out);
    }
}

// Round 11
// 133.083 us; speedup vs baseline: 1.1591x; 1.0329x over previous
//
#include <hip/hip_runtime.h>
#include <math.h>

#define BATCH 8192
#define SENTS 50
#define ED    256
#define NENT  20
#define BB    16

#define ENT_BLOCKS (BATCH / 4)     // 2048
#define AT_BLOCKS  256

// log2(200)/256
#define RATE_K 0.0298588132413075f

typedef float f4 __attribute__((ext_vector_type(4)));

// ---------------------------------------------------------------------------
// Kernel 0 (fat): blocks [0, ENT_BLOCKS) -> entity reduce (nt loads);
//                 blocks [ENT_BLOCKS, +AT_BLOCKS) -> A transpose.
// ---------------------------------------------------------------------------
__global__ __launch_bounds__(256) void ent_at_kernel(
    const float* __restrict__ entities, const float* __restrict__ dense_w,
    const float* __restrict__ A,
    float* __restrict__ m_out, float* __restrict__ AT)
{
    __shared__ float tile[16][17];
    int t = threadIdx.x;

    if (blockIdx.x < ENT_BLOCKS) {
        int b = blockIdx.x * 4 + (t >> 6);
        int c = t & 63;

        const f4* e4 = (const f4*)(entities + (size_t)b * NENT * ED);

        f4 a[NENT];
        #pragma unroll
        for (int n = 0; n < NENT; ++n)
            a[n] = __builtin_nontemporal_load(&e4[n * 64 + c]);

        f4 s = (f4)0.f;
        #pragma unroll
        for (int n = 0; n < NENT; ++n) s += a[n];

        f4 w4 = ((const f4*)dense_w)[c];
        s *= w4;
        ((f4*)(m_out + (size_t)b * ED))[c] = s;
    } else {
        int bid = blockIdx.x - ENT_BLOCKS;
        int tx = t & 15, ty = t >> 4;
        int bi = bid & 15, bj = bid >> 4;

        tile[ty][tx] = A[(bi * 16 + ty) * ED + (bj * 16 + tx)];
        __syncthreads();
        AT[(bj * 16 + ty) * ED + (bi * 16 + tx)] = tile[tx][ty];
    }
}

// ---------------------------------------------------------------------------
// Kernel 1: v[b,e'] = sum_e AT[e,e'] m[b,e]. BB batches per block;
// coalesced AT column reads (L2-resident); LDS broadcast reads of m.
// ---------------------------------------------------------------------------
__global__ __launch_bounds__(256) void matvec_kernel(
    const float* __restrict__ mws, const float* __restrict__ AT,
    float* __restrict__ vws)
{
    __shared__ __align__(16) float ml[BB][ED];

    int t  = threadIdx.x;
    int b0 = blockIdx.x * BB;

    for (int i = 0; i < BB; ++i)
        ml[i][t] = mws[(size_t)(b0 + i) * ED + t];
    __syncthreads();

    float acc[BB];
    #pragma unroll
    for (int i = 0; i < BB; ++i) acc[i] = 0.f;

    for (int e = 0; e < ED; e += 4) {
        float a0 = AT[(e + 0) * ED + t];
        float a1 = AT[(e + 1) * ED + t];
        float a2 = AT[(e + 2) * ED + t];
        float a3 = AT[(e + 3) * ED + t];
        #pragma unroll
        for (int i = 0; i < BB; ++i) {
            float4 mv = *(const float4*)&ml[i][e];
            acc[i] += mv.x * a0 + mv.y * a1 + mv.z * a2 + mv.w * a3;
        }
    }

    #pragma unroll
    for (int i = 0; i < BB; ++i)
        vws[(size_t)(b0 + i) * ED + t] = acc[i];
}

// ---------------------------------------------------------------------------
// Kernel 2: out[b] = sigmoid( sum_s coef[s] * (x[s].v[b]) + bias ),
// coef = softmax_s(x[s].x[49]). One block per batch, 4 waves; wave r owns
// rows s = r+4k, lane c owns float4 cols. x consumed at arrival.
// sents read with NONTEMPORAL loads (pure stream, no reuse).
// ---------------------------------------------------------------------------
__global__ __launch_bounds__(256) void sents_kernel(
    const float* __restrict__ sents, const float* __restrict__ vws,
    const float* __restrict__ dense_b, float* __restrict__ out)
{
    __shared__ float lgs[64];
    __shared__ float wred[4];

    int t = threadIdx.x;
    int c = t & 63;
    int r = t >> 6;
    int b = blockIdx.x;
    bool has13 = (r < 2);

    const f4* s4 = (const f4*)(sents + (size_t)b * SENTS * ED);

    f4 qv = __builtin_nontemporal_load(&s4[49 * 64 + c]);
    f4 vv = ((const f4*)(vws + (size_t)b * ED))[c];
    f4 xv[13];
    #pragma unroll
    for (int k = 0; k < 12; ++k)
        xv[k] = __builtin_nontemporal_load(&s4[(r + 4 * k) * 64 + c]);
    if (has13) xv[12] = __builtin_nontemporal_load(&s4[(r + 48) * 64 + c]);

    f4 rate;
    rate.x = exp2f(-(float)(4 * c + 0) * RATE_K);
    rate.y = exp2f(-(float)(4 * c + 1) * RATE_K);
    rate.z = exp2f(-(float)(4 * c + 2) * RATE_K);
    rate.w = exp2f(-(float)(4 * c + 3) * RATE_K);

    f4 q;
    q.x = qv.x + __sinf(49.f * rate.x);
    q.y = qv.y + __sinf(49.f * rate.y);
    q.z = qv.z + __sinf(49.f * rate.z);
    q.w = qv.w + __sinf(49.f * rate.w);

    float zp[13];
    #pragma unroll
    for (int k = 0; k < 13; ++k) {
        if (k < 12 || has13) {
            float fs = (float)(r + 4 * k);
            f4 x;
            x.x = xv[k].x + __sinf(fs * rate.x);
            x.y = xv[k].y + __sinf(fs * rate.y);
            x.z = xv[k].z + __sinf(fs * rate.z);
            x.w = xv[k].w + __sinf(fs * rate.w);

            zp[k] = x.x * vv.x + x.y * vv.y + x.z * vv.z + x.w * vv.w;

            float p = x.x * q.x + x.y * q.y + x.z * q.z + x.w * q.w;
            p += __shfl_xor(p, 1);
            p += __shfl_xor(p, 2);
            p += __shfl_xor(p, 4);
            p += __shfl_xor(p, 8);
            p += __shfl_xor(p, 16);
            p += __shfl_xor(p, 32);
            if (c == 0) lgs[r + 4 * k] = p;
        } else {
            zp[k] = 0.f;
        }
    }
    __syncthreads();

    float lg = (c < SENTS) ? lgs[c] : -INFINITY;
    float mx = lg;
    mx = fmaxf(mx, __shfl_xor(mx, 1));
    mx = fmaxf(mx, __shfl_xor(mx, 2));
    mx = fmaxf(mx, __shfl_xor(mx, 4));
    mx = fmaxf(mx, __shfl_xor(mx, 8));
    mx = fmaxf(mx, __shfl_xor(mx, 16));
    mx = fmaxf(mx, __shfl_xor(mx, 32));
    float ex = (c < SENTS) ? __expf(lg - mx) : 0.f;
    float sm = ex;
    sm += __shfl_xor(sm, 1);
    sm += __shfl_xor(sm, 2);
    sm += __shfl_xor(sm, 4);
    sm += __shfl_xor(sm, 8);
    sm += __shfl_xor(sm, 16);
    sm += __shfl_xor(sm, 32);
    float coef = ex / sm;

    float acc = 0.f;
    #pragma unroll
    for (int k = 0; k < 13; ++k) {
        if (k < 12 || has13)
            acc += __shfl(coef, r + 4 * k) * zp[k];
    }
    acc += __shfl_xor(acc, 1);
    acc += __shfl_xor(acc, 2);
    acc += __shfl_xor(acc, 4);
    acc += __shfl_xor(acc, 8);
    acc += __shfl_xor(acc, 16);
    acc += __shfl_xor(acc, 32);
    if (c == 0) wred[r] = acc;
    __syncthreads();

    if (t == 0) {
        float tot = (wred[0] + wred[1]) + (wred[2] + wred[3]);
        out[b] = 1.f / (1.f + __expf(-(tot + dense_b[0])));
    }
}

// ---------------------------------------------------------------------------
// Fallback: fully fused, no workspace (in case ws_size is tiny)
// ---------------------------------------------------------------------------
__global__ __launch_bounds__(256) void fused_kernel(
    const float* __restrict__ sents, const float* __restrict__ entities,
    const float* __restrict__ A, const float* __restrict__ dense_w,
    const float* __restrict__ dense_b, float* __restrict__ out)
{
    __shared__ __align__(16) float xs[SENTS][ED + 4];
    __shared__ float logit_s[64];
    __shared__ float coef[64];
    __shared__ __align__(16) float harr[ED];
    __shared__ float marr[ED];
    __shared__ float red[4];

    int t    = threadIdx.x;
    int b    = blockIdx.x;
    int lane = t & 63;
    int w    = t >> 6;

    float rate = exp2f(-(float)t * RATE_K);
    const float* sp = sents + (size_t)b * SENTS * ED;
    for (int s = 0; s < SENTS; ++s)
        xs[s][t] = sp[s * ED + t] + sinf((float)s * rate);
    __syncthreads();

    float4 q = *(const float4*)&xs[SENTS - 1][lane * 4];
    for (int s = w; s < SENTS; s += 4) {
        float4 v = *(const float4*)&xs[s][lane * 4];
        float p = v.x * q.x + v.y * q.y + v.z * q.z + v.w * q.w;
        p += __shfl_down(p, 32);
        p += __shfl_down(p, 16);
        p += __shfl_down(p, 8);
        p += __shfl_down(p, 4);
        p += __shfl_down(p, 2);
        p += __shfl_down(p, 1);
        if (lane == 0) logit_s[s] = p;
    }
    __syncthreads();

    if (w == 0) {
        float l = (lane < SENTS) ? logit_s[lane] : -INFINITY;
        float mx = l;
        for (int off = 32; off >= 1; off >>= 1) mx = fmaxf(mx, __shfl_xor(mx, off));
        float ex = (lane < SENTS) ? expf(l - mx) : 0.f;
        float sm = ex;
        for (int off = 32; off >= 1; off >>= 1) sm += __shfl_xor(sm, off);
        if (lane < SENTS) coef[lane] = ex / sm;
    }
    __syncthreads();

    float h = 0.f;
    #pragma unroll
    for (int s = 0; s < SENTS; ++s) h += coef[s] * xs[s][t];

    const float* ent = entities + (size_t)b * NENT * ED;
    float es = 0.f;
    #pragma unroll
    for (int n = 0; n < NENT; ++n) es += ent[n * ED + t];
    float m = es * dense_w[t];

    harr[t] = h;
    marr[t] = m;
    __syncthreads();

    float acc = 0.f;
    for (int ep = 0; ep < ED; ep += 4) {
        float4 hv = *(const float4*)&harr[ep];
        acc += hv.x * A[(ep + 0) * ED + t];
        acc += hv.y * A[(ep + 1) * ED + t];
        acc += hv.z * A[(ep + 2) * ED + t];
        acc += hv.w * A[(ep + 3) * ED + t];
    }
    float val = acc * marr[t];
    val += __shfl_down(val, 32);
    val += __shfl_down(val, 16);
    val += __shfl_down(val, 8);
    val += __shfl_down(val, 4);
    val += __shfl_down(val, 2);
    val += __shfl_down(val, 1);
    if (lane == 0) red[w] = val;
    __syncthreads();
    if (t == 0) {
        float tot = red[0] + red[1] + red[2] + red[3];
        out[b] = 1.f / (1.f + expf(-(tot + dense_b[0])));
    }
}

extern "C" void kernel_launch(void* const* d_in, const int* in_sizes, int n_in,
                              void* d_out, int out_size, void* d_ws, size_t ws_size,
                              hipStream_t stream) {
    const float* sents    = (const float*)d_in[0];
    const float* entities = (const float*)d_in[1];
    const float* A        = (const float*)d_in[2];
    const float* dense_w  = (const float*)d_in[3];
    const float* dense_b  = (const float*)d_in[4];
    float* out = (float*)d_out;

    size_t hm_bytes = (size_t)BATCH * ED * sizeof(float);           // 8 MB each
    size_t at_bytes = (size_t)ED * ED * sizeof(float);              // 256 KB
    size_t need = 2 * hm_bytes + at_bytes;

    if (ws_size >= need) {
        float* mws = (float*)d_ws;
        float* vws = (float*)((char*)d_ws + hm_bytes);
        float* ATw = (float*)((char*)d_ws + 2 * hm_bytes);
        ent_at_kernel<<<ENT_BLOCKS + AT_BLOCKS, 256, 0, stream>>>(
            entities, dense_w, A, mws, ATw);
        matvec_kernel<<<BATCH / BB, 256, 0, stream>>>(mws, ATw, vws);
        sents_kernel<<<BATCH, 256, 0, stream>>>(sents, vws, dense_b, out);
    } else {
        fused_kernel<<<BATCH, 256, 0, stream>>>(sents, entities, A, dense_w, dense_b, out);
    }
}

// Round 12
// 132.752 us; speedup vs baseline: 1.1620x; 1.0025x over previous
//
#include <hip/hip_runtime.h>
#include <math.h>

#define BATCH 8192
#define SENTS 50
#define ED    256
#define NENT  20
#define BB    16

#define SENT_BLOCKS BATCH            // 8192
#define ENT_BLOCKS  (BATCH / 4)      // 2048

// log2(200)/256
#define RATE_K 0.0298588132413075f

typedef float f4 __attribute__((ext_vector_type(4)));

// ---------------------------------------------------------------------------
// Kernel 1 (fat): blocks [0, SENT_BLOCKS) -> h[b] (attention, nt loads);
//                 blocks [SENT_BLOCKS, +ENT_BLOCKS) -> m[b] (ent reduce, nt).
// sents branch: 4 waves; wave r owns rows s=r+4k; per-wave local softmax
// partial (mr, dr, hacc) -> LDS -> ONE barrier -> log-sum-exp merge -> h.
// ---------------------------------------------------------------------------
__global__ __launch_bounds__(256) void fat_kernel(
    const float* __restrict__ sents, const float* __restrict__ entities,
    const float* __restrict__ dense_w,
    float* __restrict__ h_out, float* __restrict__ m_out)
{
    __shared__ __align__(16) float hp[4][ED];
    __shared__ float md[4][2];

    int t = threadIdx.x;

    if (blockIdx.x < SENT_BLOCKS) {
        int b = blockIdx.x;
        int c = t & 63;
        int r = t >> 6;           // wave id = row residue 0..3
        bool has13 = (r < 2);     // k=12 row: 48 (r=0), 49 (r=1)

        const f4* s4 = (const f4*)(sents + (size_t)b * SENTS * ED);

        // ---- issue all loads up front (nt: pure stream) ----
        f4 qv = __builtin_nontemporal_load(&s4[49 * 64 + c]);
        f4 xv[13];
        #pragma unroll
        for (int k = 0; k < 12; ++k)
            xv[k] = __builtin_nontemporal_load(&s4[(r + 4 * k) * 64 + c]);
        if (has13) xv[12] = __builtin_nontemporal_load(&s4[(r + 48) * 64 + c]);

        // ---- per-lane rates (VALU under load latency) ----
        f4 rate;
        rate.x = exp2f(-(float)(4 * c + 0) * RATE_K);
        rate.y = exp2f(-(float)(4 * c + 1) * RATE_K);
        rate.z = exp2f(-(float)(4 * c + 2) * RATE_K);
        rate.w = exp2f(-(float)(4 * c + 3) * RATE_K);

        f4 q;
        q.x = qv.x + __sinf(49.f * rate.x);
        q.y = qv.y + __sinf(49.f * rate.y);
        q.z = qv.z + __sinf(49.f * rate.z);
        q.w = qv.w + __sinf(49.f * rate.w);

        // ---- x = sents + pos; per-row logits via butterfly ----
        f4 x[13];
        float lg[13];
        #pragma unroll
        for (int k = 0; k < 13; ++k) {
            if (k < 12 || has13) {
                float fs = (float)(r + 4 * k);
                x[k].x = xv[k].x + __sinf(fs * rate.x);
                x[k].y = xv[k].y + __sinf(fs * rate.y);
                x[k].z = xv[k].z + __sinf(fs * rate.z);
                x[k].w = xv[k].w + __sinf(fs * rate.w);
                float p = x[k].x * q.x + x[k].y * q.y + x[k].z * q.z + x[k].w * q.w;
                p += __shfl_xor(p, 1);
                p += __shfl_xor(p, 2);
                p += __shfl_xor(p, 4);
                p += __shfl_xor(p, 8);
                p += __shfl_xor(p, 16);
                p += __shfl_xor(p, 32);
                lg[k] = p;
            }
        }

        // ---- wave-local softmax partial ----
        float mr = lg[0];
        #pragma unroll
        for (int k = 1; k < 13; ++k)
            if (k < 12 || has13) mr = fmaxf(mr, lg[k]);

        float dr = 0.f;
        f4 hacc = (f4)0.f;
        #pragma unroll
        for (int k = 0; k < 13; ++k) {
            if (k < 12 || has13) {
                float w = __expf(lg[k] - mr);
                dr += w;
                hacc.x += w * x[k].x; hacc.y += w * x[k].y;
                hacc.z += w * x[k].z; hacc.w += w * x[k].w;
            }
        }

        *(f4*)&hp[r][4 * c] = hacc;
        if (c == 0) { md[r][0] = mr; md[r][1] = dr; }
        __syncthreads();

        // ---- LSE merge across 4 waves; thread t owns column t ----
        float m0 = md[0][0], d0 = md[0][1];
        float m1 = md[1][0], d1 = md[1][1];
        float m2 = md[2][0], d2 = md[2][1];
        float m3 = md[3][0], d3 = md[3][1];
        float M  = fmaxf(fmaxf(m0, m1), fmaxf(m2, m3));
        float s0 = __expf(m0 - M), s1 = __expf(m1 - M);
        float s2 = __expf(m2 - M), s3 = __expf(m3 - M);
        float dd = s0 * d0 + s1 * d1 + s2 * d2 + s3 * d3;
        float hv = s0 * hp[0][t] + s1 * hp[1][t] + s2 * hp[2][t] + s3 * hp[3][t];
        h_out[(size_t)b * ED + t] = hv / dd;
    } else {
        int b = (blockIdx.x - SENT_BLOCKS) * 4 + (t >> 6);
        int c = t & 63;

        const f4* e4 = (const f4*)(entities + (size_t)b * NENT * ED);

        f4 a[NENT];
        #pragma unroll
        for (int n = 0; n < NENT; ++n)
            a[n] = __builtin_nontemporal_load(&e4[n * 64 + c]);

        f4 s = (f4)0.f;
        #pragma unroll
        for (int n = 0; n < NENT; ++n) s += a[n];

        f4 w4 = ((const f4*)dense_w)[c];
        s *= w4;
        ((f4*)(m_out + (size_t)b * ED))[c] = s;
    }
}

// ---------------------------------------------------------------------------
// Kernel 2: out[b] = sigmoid( sum_e' h[e'] * sum_e A[e',e] m[e] + bias )
//         = sigmoid( sum_t (sum_e' h[e'] A[e',t]) * m[t] + bias ).
// BB batches per block; coalesced row reads of A (L2-resident, no transpose).
// ---------------------------------------------------------------------------
__global__ __launch_bounds__(256) void bilinear_kernel(
    const float* __restrict__ hws, const float* __restrict__ mws,
    const float* __restrict__ A, const float* __restrict__ dense_b,
    float* __restrict__ out)
{
    __shared__ __align__(16) float hl[BB][ED];
    __shared__ float ml[BB][ED];
    __shared__ float part[BB][ED];

    int t  = threadIdx.x;
    int b0 = blockIdx.x * BB;

    for (int i = 0; i < BB; ++i) {
        hl[i][t] = hws[(size_t)(b0 + i) * ED + t];
        ml[i][t] = mws[(size_t)(b0 + i) * ED + t];
    }
    __syncthreads();

    float acc[BB];
    #pragma unroll
    for (int i = 0; i < BB; ++i) acc[i] = 0.f;

    for (int ep = 0; ep < ED; ep += 4) {
        float a0 = A[(ep + 0) * ED + t];
        float a1 = A[(ep + 1) * ED + t];
        float a2 = A[(ep + 2) * ED + t];
        float a3 = A[(ep + 3) * ED + t];
        #pragma unroll
        for (int i = 0; i < BB; ++i) {
            float4 hv = *(const float4*)&hl[i][ep];
            acc[i] += hv.x * a0 + hv.y * a1 + hv.z * a2 + hv.w * a3;
        }
    }

    #pragma unroll
    for (int i = 0; i < BB; ++i) part[i][t] = acc[i] * ml[i][t];
    __syncthreads();

    int lane = t & 63, w = t >> 6;
    float bias = dense_b[0];
    for (int i = w; i < BB; i += 4) {
        float v = part[i][lane] + part[i][lane + 64] + part[i][lane + 128] + part[i][lane + 192];
        for (int off = 32; off >= 1; off >>= 1) v += __shfl_xor(v, off);
        if (lane == 0) out[b0 + i] = 1.f / (1.f + __expf(-(v + bias)));
    }
}

// ---------------------------------------------------------------------------
// Fallback: fully fused, no workspace (in case ws_size is tiny)
// ---------------------------------------------------------------------------
__global__ __launch_bounds__(256) void fused_kernel(
    const float* __restrict__ sents, const float* __restrict__ entities,
    const float* __restrict__ A, const float* __restrict__ dense_w,
    const float* __restrict__ dense_b, float* __restrict__ out)
{
    __shared__ __align__(16) float xs[SENTS][ED + 4];
    __shared__ float logit_s[64];
    __shared__ float coef[64];
    __shared__ __align__(16) float harr[ED];
    __shared__ float marr[ED];
    __shared__ float red[4];

    int t    = threadIdx.x;
    int b    = blockIdx.x;
    int lane = t & 63;
    int w    = t >> 6;

    float rate = exp2f(-(float)t * RATE_K);
    const float* sp = sents + (size_t)b * SENTS * ED;
    for (int s = 0; s < SENTS; ++s)
        xs[s][t] = sp[s * ED + t] + sinf((float)s * rate);
    __syncthreads();

    float4 q = *(const float4*)&xs[SENTS - 1][lane * 4];
    for (int s = w; s < SENTS; s += 4) {
        float4 v = *(const float4*)&xs[s][lane * 4];
        float p = v.x * q.x + v.y * q.y + v.z * q.z + v.w * q.w;
        p += __shfl_down(p, 32);
        p += __shfl_down(p, 16);
        p += __shfl_down(p, 8);
        p += __shfl_down(p, 4);
        p += __shfl_down(p, 2);
        p += __shfl_down(p, 1);
        if (lane == 0) logit_s[s] = p;
    }
    __syncthreads();

    if (w == 0) {
        float l = (lane < SENTS) ? logit_s[lane] : -INFINITY;
        float mx = l;
        for (int off = 32; off >= 1; off >>= 1) mx = fmaxf(mx, __shfl_xor(mx, off));
        float ex = (lane < SENTS) ? expf(l - mx) : 0.f;
        float sm = ex;
        for (int off = 32; off >= 1; off >>= 1) sm += __shfl_xor(sm, off);
        if (lane < SENTS) coef[lane] = ex / sm;
    }
    __syncthreads();

    float h = 0.f;
    #pragma unroll
    for (int s = 0; s < SENTS; ++s) h += coef[s] * xs[s][t];

    const float* ent = entities + (size_t)b * NENT * ED;
    float es = 0.f;
    #pragma unroll
    for (int n = 0; n < NENT; ++n) es += ent[n * ED + t];
    float m = es * dense_w[t];

    harr[t] = h;
    marr[t] = m;
    __syncthreads();

    float acc = 0.f;
    for (int ep = 0; ep < ED; ep += 4) {
        float4 hv = *(const float4*)&harr[ep];
        acc += hv.x * A[(ep + 0) * ED + t];
        acc += hv.y * A[(ep + 1) * ED + t];
        acc += hv.z * A[(ep + 2) * ED + t];
        acc += hv.w * A[(ep + 3) * ED + t];
    }
    float val = acc * marr[t];
    val += __shfl_down(val, 32);
    val += __shfl_down(val, 16);
    val += __shfl_down(val, 8);
    val += __shfl_down(val, 4);
    val += __shfl_down(val, 2);
    val += __shfl_down(val, 1);
    if (lane == 0) red[w] = val;
    __syncthreads();
    if (t == 0) {
        float tot = red[0] + red[1] + red[2] + red[3];
        out[b] = 1.f / (1.f + expf(-(tot + dense_b[0])));
    }
}

extern "C" void kernel_launch(void* const* d_in, const int* in_sizes, int n_in,
                              void* d_out, int out_size, void* d_ws, size_t ws_size,
                              hipStream_t stream) {
    const float* sents    = (const float*)d_in[0];
    const float* entities = (const float*)d_in[1];
    const float* A        = (const float*)d_in[2];
    const float* dense_w  = (const float*)d_in[3];
    const float* dense_b  = (const float*)d_in[4];
    float* out = (float*)d_out;

    size_t hm_bytes = (size_t)BATCH * ED * sizeof(float);           // 8 MB each
    size_t need = 2 * hm_bytes;

    if (ws_size >= need) {
        float* hws = (float*)d_ws;
        float* mws = (float*)((char*)d_ws + hm_bytes);
        fat_kernel<<<SENT_BLOCKS + ENT_BLOCKS, 256, 0, stream>>>(
            sents, entities, dense_w, hws, mws);
        bilinear_kernel<<<BATCH / BB, 256, 0, stream>>>(hws, mws, A, dense_b, out);
    } else {
        fused_kernel<<<BATCH, 256, 0, stream>>>(sents, entities, A, dense_w, dense_b, out);
    }
}